// Round 8
// baseline (497.263 us; speedup 1.0000x reference)
//
#include <hip/hip_runtime.h>
#include <hip/hip_bf16.h>

#define BS    128
#define HDIM  512
#define NNODE 1024
#define BN    32                 // nodes per tile
#define TPB   8                  // tiles per block (block covers 256 nodes)
#define NTB   4                  // blocks per batch
#define NBLK  (BS*NTB)           // 512 blocks
#define NTHR  512                // 8 waves

typedef __bf16 bf16x8 __attribute__((ext_vector_type(8)));
typedef float  f32x4  __attribute__((ext_vector_type(4)));

__device__ __forceinline__ unsigned short f2bf(float x) {
    unsigned int u = __builtin_bit_cast(unsigned int, x);
    unsigned int r = (u + 0x7FFFu + ((u >> 16) & 1u)) >> 16;
    return (unsigned short)r;
}

__device__ __forceinline__ unsigned int cvt_pk_bf16(float lo, float hi) {
    unsigned int r;
    asm("v_cvt_pk_bf16_f32 %0, %1, %2" : "=v"(r) : "v"(lo), "v"(hi));
    return r;
}

__device__ __forceinline__ float tanh_fast(float x) {
    float e = __expf(2.0f * x);
    return 1.0f - 2.0f / (e + 1.0f);
}

// ---- kernel 1: cast W_ref (f32 [512][512]) -> bf16 ----
__global__ void k_cast_w(const float* __restrict__ W, unsigned short* __restrict__ Wb) {
    int i = (blockIdx.x * 256 + threadIdx.x) * 4;
    float4 v = *(const float4*)(W + i);
    ushort4 o;
    o.x = f2bf(v.x); o.y = f2bf(v.y); o.z = f2bf(v.z); o.w = f2bf(v.w);
    *(ushort4*)(Wb + i) = o;
}

// ---- kernel 2: u1b[b][o] = (q @ W_q^T + b_q + b_ref)[b][o]  (fp32, feeds tanh) ----
__global__ void k_u1(const float* __restrict__ q, const float* __restrict__ Wq,
                     const float* __restrict__ bq, const float* __restrict__ bref,
                     float* __restrict__ u1b) {
    __shared__ float ql[HDIM];
    int b = blockIdx.x, o = threadIdx.x;
    ql[o] = q[b * HDIM + o];
    __syncthreads();
    float acc = bq[o] + bref[o];   // b_ref inside tanh(u1+u2)
    const float* wr = Wq + (size_t)o * HDIM;
    #pragma unroll 4
    for (int h = 0; h < HDIM; h += 4) {
        float4 w = *(const float4*)(wr + h);
        acc += w.x * ql[h] + w.y * ql[h + 1] + w.z * ql[h + 2] + w.w * ql[h + 3];
    }
    u1b[b * HDIM + o] = acc;
}

// ---- kernel 3: main fused kernel ----
// 512 thr = 8 waves; wave owns 64 rows: acc[4][2] = 32 acc-regs. BN=32, TPB=8.
// Online softmax across the block's 8 tiles: running (M,S) + per-thread D[4][4]
// rescaled by fD = exp(M_old - M_new) each tile. LDS ~70 KB, target 2 blocks/CU.
// Double-buffered 2x32KB tile; t+1 staged in two G[4] halves woven into GEMM(t).
__launch_bounds__(NTHR, 4)
__global__ void k_main(const float* __restrict__ ref, const int* __restrict__ mask,
                       const float* __restrict__ v, const unsigned short* __restrict__ Wb,
                       const float* __restrict__ u1b,
                       float* __restrict__ stats, float* __restrict__ dts)
{
    __shared__ unsigned short Bs[2][BN * 512];  // 2 x 32 KB, XOR-swizzled [n][k]
    __shared__ float u1l[HDIM];
    __shared__ float vl[HDIM];
    __shared__ float sred[8 * BN];
    __shared__ float wts[BN];
    __shared__ float fD_lds;
    __shared__ int   maskl[TPB * BN];

    const int bid  = blockIdx.x;
    const int b    = bid >> 2;
    const int q4   = bid & 3;
    const int tid  = threadIdx.x;
    const int wave = tid >> 6;
    const int lane = tid & 63;
    const int cl   = lane & 15;
    const int gr   = lane >> 4;
    const int wo   = wave * 64;

    u1l[tid] = u1b[b * HDIM + tid];
    vl[tid]  = v[tid];
    if (tid < TPB * BN) maskl[tid] = mask[b * NNODE + q4 * (TPB * BN) + tid];

    // staging: thread owns 8 h-rows x 4 n-cols of the 512h x 32n tile (2 halves of 4 rows)
    const int sn = (tid & 7) * 4;         // n base (0..28)
    const int sh = (tid >> 3) * 8;        // h base (0..504); thread's slot = tid>>3
    const int slotb = tid >> 3;
    const float* refq = ref + (size_t)b * HDIM * NNODE + (size_t)sh * NNODE
                            + q4 * (TPB * BN) + sn;

    float4 G[4];
    auto issue_half = [&](int t, int half) {
        const float* p = refq + t * BN + (size_t)(half * 4) * NNODE;
        #pragma unroll
        for (int j = 0; j < 4; j++)
            G[j] = *(const float4*)(p + (size_t)j * NNODE);
    };
    auto commit_half = [&](int buf, int half) {
        #pragma unroll
        for (int c = 0; c < 4; c++) {
            const int nn = sn + c;
            const int swz = (nn ^ (nn >> 3)) & 7;
            uint2 w;
            w.x = cvt_pk_bf16(((const float*)&G[0])[c], ((const float*)&G[1])[c]);
            w.y = cvt_pk_bf16(((const float*)&G[2])[c], ((const float*)&G[3])[c]);
            *(uint2*)&Bs[buf][nn * 512 + (slotb ^ swz) * 8 + half * 4] = w;
        }
    };

    const unsigned short* wpa = Wb + (size_t)(wo + cl) * 512 + gr * 8;

    // online-softmax state
    float M_run = -3.4e38f, S_run = 0.f;
    float D[4][4];
    #pragma unroll
    for (int m = 0; m < 4; m++)
        #pragma unroll
        for (int r = 0; r < 4; r++) D[m][r] = 0.f;

    // prologue: stage tile 0 into buf 0
    issue_half(0, 0); commit_half(0, 0);
    issue_half(0, 1); commit_half(0, 1);
    __syncthreads();

    for (int t = 0; t < TPB; t++) {
        const int cur = t & 1, nxt = cur ^ 1;
        const bool more = (t + 1 < TPB);
        if (more) issue_half(t + 1, 0);

        f32x4 acc[4][2];
        #pragma unroll
        for (int m = 0; m < 4; m++)
            #pragma unroll
            for (int nf = 0; nf < 2; nf++)
                acc[m][nf] = (f32x4){0.f, 0.f, 0.f, 0.f};

        bf16x8 A[4], B[2];
        auto lda = [&](int kks) {
            #pragma unroll
            for (int m = 0; m < 4; m++)
                A[m] = *(const bf16x8*)(wpa + (size_t)m * 16 * 512 + kks * 32);
        };
        auto ldb = [&](int kks) {
            #pragma unroll
            for (int nf = 0; nf < 2; nf++) {
                int n = nf * 16 + cl;
                int slot = ((kks << 2) + gr) ^ ((n ^ (n >> 3)) & 7);
                B[nf] = *(const bf16x8*)&Bs[cur][n * 512 + slot * 8];
            }
        };

        #pragma unroll
        for (int kk = 0; kk < 16; kk++) {
            if (kk == 8 && more) {
                commit_half(nxt, 0);
                issue_half(t + 1, 1);
            }
            lda(kk);
            ldb(kk);
            #pragma unroll
            for (int m = 0; m < 4; m++)
                #pragma unroll
                for (int nf = 0; nf < 2; nf++)
                    acc[m][nf] = __builtin_amdgcn_mfma_f32_16x16x32_bf16(A[m], B[nf], acc[m][nf], 0, 0, 0);
        }
        if (more) commit_half(nxt, 1);

        // ---- scores: sp[nf] = sum over wave's 64 rows of v[o]*tanh(u1[o]+u2) ----
        float sp[2] = {0.f, 0.f};
        #pragma unroll
        for (int m = 0; m < 4; m++) {
            #pragma unroll
            for (int r = 0; r < 4; r++) {
                int o = wo + m * 16 + gr * 4 + r;
                float uo = u1l[o];
                float vv = vl[o];
                #pragma unroll
                for (int nf = 0; nf < 2; nf++)
                    sp[nf] += vv * tanh_fast(uo + acc[m][nf][r]);
            }
        }
        #pragma unroll
        for (int nf = 0; nf < 2; nf++) {
            sp[nf] += __shfl_xor(sp[nf], 16);
            sp[nf] += __shfl_xor(sp[nf], 32);
        }
        if (lane < 16) {
            #pragma unroll
            for (int nf = 0; nf < 2; nf++)
                sred[wave * BN + nf * 16 + lane] = sp[nf];
        }
        __syncthreads();   // barB: sred ready; all reads of Bs[cur] done

        // wave0: masked online softmax over this tile's 32 nodes
        if (wave == 0 && lane < 32) {
            float u = 0.f;
            #pragma unroll
            for (int w = 0; w < 8; w++) u += sred[w * BN + lane];
            u -= 1e8f * (float)maskl[t * BN + lane];
            float mx = u;
            #pragma unroll
            for (int off = 1; off < 32; off <<= 1) mx = fmaxf(mx, __shfl_xor(mx, off));
            float Mp = fmaxf(M_run, mx);
            float wv = __expf(u - Mp);
            float s = wv;
            #pragma unroll
            for (int off = 1; off < 32; off <<= 1) s += __shfl_xor(s, off);
            float fD = __expf(M_run - Mp);
            S_run = S_run * fD + s;
            M_run = Mp;
            wts[lane] = wv;
            if (lane == 0) fD_lds = fD;
        }
        __syncthreads();   // barC: wts + fD ready; Bs[nxt] committed

        // ---- D[m][r] = D*fD + sum_n acc[.][n]*wts[n] ----
        const float fDv = fD_lds;
        float wc[2];
        #pragma unroll
        for (int nf = 0; nf < 2; nf++) wc[nf] = wts[nf * 16 + cl];
        #pragma unroll
        for (int m = 0; m < 4; m++) {
            #pragma unroll
            for (int r = 0; r < 4; r++) {
                float d = acc[m][0][r] * wc[0] + acc[m][1][r] * wc[1];
                d += __shfl_xor(d, 1);
                d += __shfl_xor(d, 2);
                d += __shfl_xor(d, 4);
                d += __shfl_xor(d, 8);
                D[m][r] = D[m][r] * fDv + d;
            }
        }
    }

    // ---- write per-block results ----
    float* dout = dts + (size_t)bid * HDIM;
    #pragma unroll
    for (int m = 0; m < 4; m++)
        #pragma unroll
        for (int r = 0; r < 4; r++)
            if (cl == 0) dout[wo + m * 16 + gr * 4 + r] = D[m][r];
    if (tid == 0) {
        stats[bid * 2]     = M_run;
        stats[bid * 2 + 1] = S_run;
    }
}

// ---- kernel 4: combine 4 block-quarters per batch ----
__global__ void k_comb(const float* __restrict__ stats, const float* __restrict__ dts,
                       const float* __restrict__ bref, float* __restrict__ out) {
    __shared__ float sm[NTB], sl[NTB];
    int b = blockIdx.x, tid = threadIdx.x;
    if (tid < NTB) {
        sm[tid] = stats[(b * NTB + tid) * 2];
        sl[tid] = stats[(b * NTB + tid) * 2 + 1];
    }
    __syncthreads();
    float m = -3.4e38f;
    #pragma unroll
    for (int j = 0; j < NTB; j++) m = fmaxf(m, sm[j]);
    float sc[NTB];
    float L = 0.f;
    #pragma unroll
    for (int j = 0; j < NTB; j++) { sc[j] = __expf(sm[j] - m); L += sc[j] * sl[j]; }
    float inv = 1.0f / L;
    float acc = 0.f;
    #pragma unroll
    for (int j = 0; j < NTB; j++)
        acc += sc[j] * dts[((size_t)b * NTB + j) * HDIM + tid];
    out[b * HDIM + tid] = acc * inv + bref[tid];
}

extern "C" void kernel_launch(void* const* d_in, const int* in_sizes, int n_in,
                              void* d_out, int out_size, void* d_ws, size_t ws_size,
                              hipStream_t stream) {
    const float* q    = (const float*)d_in[0];
    const float* ref  = (const float*)d_in[1];
    const int*   mask = (const int*)d_in[2];
    const float* v    = (const float*)d_in[3];
    const float* Wq   = (const float*)d_in[4];
    const float* bq   = (const float*)d_in[5];
    const float* Wref = (const float*)d_in[6];
    const float* bref = (const float*)d_in[7];
    float* out = (float*)d_out;

    char* ws = (char*)d_ws;
    unsigned short* wbf = (unsigned short*)ws;                 // 524288 B
    float* u1b   = (float*)(ws + 524288);                      // 262144 B
    float* stats = (float*)(ws + 524288 + 262144);             // 4096 B
    float* dts   = (float*)(ws + 524288 + 262144 + 4096);      // 1 MB

    k_cast_w<<<256, 256, 0, stream>>>(Wref, wbf);
    k_u1<<<BS, HDIM, 0, stream>>>(q, Wq, bq, bref, u1b);
    k_main<<<NBLK, NTHR, 0, stream>>>(ref, mask, v, wbf, u1b, stats, dts);
    k_comb<<<BS, HDIM, 0, stream>>>(stats, dts, bref, out);
}

// Round 9
// 440.887 us; speedup vs baseline: 1.1279x; 1.1279x over previous
//
#include <hip/hip_runtime.h>
#include <hip/hip_bf16.h>

#define BS    128
#define HDIM  512
#define NNODE 1024
#define BN    32                 // nodes per tile
#define TPB   8                  // tiles per block (block covers 256 nodes)
#define NTB   4                  // blocks per batch
#define NBLK  (BS*NTB)           // 512 blocks
#define NTHR  512                // 8 waves

typedef __bf16 bf16x8 __attribute__((ext_vector_type(8)));
typedef float  f32x4  __attribute__((ext_vector_type(4)));

__device__ __forceinline__ unsigned short f2bf(float x) {
    unsigned int u = __builtin_bit_cast(unsigned int, x);
    unsigned int r = (u + 0x7FFFu + ((u >> 16) & 1u)) >> 16;
    return (unsigned short)r;
}

__device__ __forceinline__ unsigned int cvt_pk_bf16(float lo, float hi) {
    unsigned int r;
    asm("v_cvt_pk_bf16_f32 %0, %1, %2" : "=v"(r) : "v"(lo), "v"(hi));
    return r;
}

__device__ __forceinline__ float tanh_fast(float x) {
    float e = __expf(2.0f * x);
    return 1.0f - 2.0f / (e + 1.0f);
}

// ---- kernel 1: cast W_ref (f32 [512][512]) -> bf16 ----
__global__ void k_cast_w(const float* __restrict__ W, unsigned short* __restrict__ Wb) {
    int i = (blockIdx.x * 256 + threadIdx.x) * 4;
    float4 v = *(const float4*)(W + i);
    ushort4 o;
    o.x = f2bf(v.x); o.y = f2bf(v.y); o.z = f2bf(v.z); o.w = f2bf(v.w);
    *(ushort4*)(Wb + i) = o;
}

// ---- kernel 2: u1b[b][o] = (q @ W_q^T + b_q + b_ref)[b][o]  (fp32, feeds tanh) ----
__global__ void k_u1(const float* __restrict__ q, const float* __restrict__ Wq,
                     const float* __restrict__ bq, const float* __restrict__ bref,
                     float* __restrict__ u1b) {
    __shared__ float ql[HDIM];
    int b = blockIdx.x, o = threadIdx.x;
    ql[o] = q[b * HDIM + o];
    __syncthreads();
    float acc = bq[o] + bref[o];   // b_ref inside tanh(u1+u2)
    const float* wr = Wq + (size_t)o * HDIM;
    #pragma unroll 4
    for (int h = 0; h < HDIM; h += 4) {
        float4 w = *(const float4*)(wr + h);
        acc += w.x * ql[h] + w.y * ql[h + 1] + w.z * ql[h + 2] + w.w * ql[h + 3];
    }
    u1b[b * HDIM + o] = acc;
}

// ---- kernel 3: main fused kernel ----
// 512 thr = 8 waves; wave owns 64 rows: acc[4][2] = 32 acc-regs. BN=32, TPB=8.
// No min-waves bound: natural alloc (~90 arch + 32 AGPR <= 128 total) -> 2 blocks/CU
// without the (512,4) arch-VGPR clamp that spilled in round 8.
// ref staged with NON-TEMPORAL loads (read-once) so W_ref stays L2-resident.
// ONE barrier per tile: all-wave-redundant online softmax from double-buffered sred.
__launch_bounds__(NTHR)
__global__ void k_main(const float* __restrict__ ref, const int* __restrict__ mask,
                       const float* __restrict__ v, const unsigned short* __restrict__ Wb,
                       const float* __restrict__ u1b,
                       float* __restrict__ stats, float* __restrict__ dts)
{
    __shared__ unsigned short Bs[2][BN * 512];  // 2 x 32 KB, XOR-swizzled [n][k]
    __shared__ float u1l[HDIM];
    __shared__ float vl[HDIM];
    __shared__ float sred[2][8 * BN];           // double-buffered score partials
    __shared__ int   maskl[TPB * BN];

    const int bid  = blockIdx.x;
    const int b    = bid >> 2;
    const int q4   = bid & 3;
    const int tid  = threadIdx.x;
    const int wave = tid >> 6;
    const int lane = tid & 63;
    const int cl   = lane & 15;
    const int gr   = lane >> 4;
    const int wo   = wave * 64;
    const int ln32 = lane & 31;

    u1l[tid] = u1b[b * HDIM + tid];
    vl[tid]  = v[tid];
    if (tid < TPB * BN) maskl[tid] = mask[b * NNODE + q4 * (TPB * BN) + tid];

    // staging: thread owns 8 h-rows x 4 n-cols of the 512h x 32n tile (2 halves of 4 rows)
    const int sn = (tid & 7) * 4;         // n base (0..28)
    const int sh = (tid >> 3) * 8;        // h base (0..504)
    const int slotb = tid >> 3;
    const float* refq = ref + (size_t)b * HDIM * NNODE + (size_t)sh * NNODE
                            + q4 * (TPB * BN) + sn;

    f32x4 G[4];
    auto issue_half = [&](int t, int half) {
        const float* p = refq + t * BN + (size_t)(half * 4) * NNODE;
        #pragma unroll
        for (int j = 0; j < 4; j++)
            G[j] = __builtin_nontemporal_load((const f32x4*)(p + (size_t)j * NNODE));
    };
    auto commit_half = [&](int buf, int half) {
        #pragma unroll
        for (int c = 0; c < 4; c++) {
            const int nn = sn + c;
            const int swz = (nn ^ (nn >> 3)) & 7;
            uint2 w;
            w.x = cvt_pk_bf16(G[0][c], G[1][c]);
            w.y = cvt_pk_bf16(G[2][c], G[3][c]);
            *(uint2*)&Bs[buf][nn * 512 + (slotb ^ swz) * 8 + half * 4] = w;
        }
    };

    const unsigned short* wpa = Wb + (size_t)(wo + cl) * 512 + gr * 8;

    // online-softmax state (tracked redundantly by all lanes)
    float M_run = -3.4e38f, S_run = 0.f;
    float D[4][4];
    #pragma unroll
    for (int m = 0; m < 4; m++)
        #pragma unroll
        for (int r = 0; r < 4; r++) D[m][r] = 0.f;

    // prologue: stage tile 0 into buf 0
    issue_half(0, 0); commit_half(0, 0);
    issue_half(0, 1); commit_half(0, 1);
    __syncthreads();

    for (int t = 0; t < TPB; t++) {
        const int cur = t & 1, nxt = cur ^ 1;
        const bool more = (t + 1 < TPB);
        if (more) issue_half(t + 1, 0);

        f32x4 acc[4][2];
        #pragma unroll
        for (int m = 0; m < 4; m++)
            #pragma unroll
            for (int nf = 0; nf < 2; nf++)
                acc[m][nf] = (f32x4){0.f, 0.f, 0.f, 0.f};

        bf16x8 A[4], B[2];
        auto lda = [&](int kks) {
            #pragma unroll
            for (int m = 0; m < 4; m++)
                A[m] = *(const bf16x8*)(wpa + (size_t)m * 16 * 512 + kks * 32);
        };
        auto ldb = [&](int kks) {
            #pragma unroll
            for (int nf = 0; nf < 2; nf++) {
                int n = nf * 16 + cl;
                int slot = ((kks << 2) + gr) ^ ((n ^ (n >> 3)) & 7);
                B[nf] = *(const bf16x8*)&Bs[cur][n * 512 + slot * 8];
            }
        };

        #pragma unroll
        for (int kk = 0; kk < 16; kk++) {
            if (kk == 8 && more) {
                commit_half(nxt, 0);
                issue_half(t + 1, 1);
            }
            lda(kk);
            ldb(kk);
            #pragma unroll
            for (int m = 0; m < 4; m++)
                #pragma unroll
                for (int nf = 0; nf < 2; nf++)
                    acc[m][nf] = __builtin_amdgcn_mfma_f32_16x16x32_bf16(A[m], B[nf], acc[m][nf], 0, 0, 0);
        }
        if (more) commit_half(nxt, 1);

        // ---- scores: sp[nf] = sum over wave's 64 rows of v[o]*tanh(u1[o]+u2) ----
        float sp[2] = {0.f, 0.f};
        #pragma unroll
        for (int m = 0; m < 4; m++) {
            #pragma unroll
            for (int r = 0; r < 4; r++) {
                int o = wo + m * 16 + gr * 4 + r;
                float uo = u1l[o];
                float vv = vl[o];
                #pragma unroll
                for (int nf = 0; nf < 2; nf++)
                    sp[nf] += vv * tanh_fast(uo + acc[m][nf][r]);
            }
        }
        #pragma unroll
        for (int nf = 0; nf < 2; nf++) {
            sp[nf] += __shfl_xor(sp[nf], 16);
            sp[nf] += __shfl_xor(sp[nf], 32);
        }
        if (lane < 16) {
            #pragma unroll
            for (int nf = 0; nf < 2; nf++)
                sred[cur][wave * BN + nf * 16 + lane] = sp[nf];
        }
        __syncthreads();   // barB (single barrier): sred[cur] ready; Bs[cur] reads done

        // ---- all-wave redundant masked online softmax over this tile's 32 nodes ----
        float u = 0.f;
        #pragma unroll
        for (int w = 0; w < 8; w++) u += sred[cur][w * BN + ln32];
        u -= 1e8f * (float)maskl[t * BN + ln32];
        float mx = u;
        #pragma unroll
        for (int off = 1; off < 32; off <<= 1) mx = fmaxf(mx, __shfl_xor(mx, off));
        float Mp = fmaxf(M_run, mx);
        float wv = __expf(u - Mp);
        float s = wv;
        #pragma unroll
        for (int off = 1; off < 32; off <<= 1) s += __shfl_xor(s, off);
        float fD = __expf(M_run - Mp);
        S_run = S_run * fD + s;
        M_run = Mp;
        float wc0 = __shfl(wv, cl);        // weight of node cl
        float wc1 = __shfl(wv, 16 + cl);   // weight of node 16+cl

        // ---- D[m][r] = D*fD + sum_n acc[.][n]*w_n ----
        #pragma unroll
        for (int m = 0; m < 4; m++) {
            #pragma unroll
            for (int r = 0; r < 4; r++) {
                float d = acc[m][0][r] * wc0 + acc[m][1][r] * wc1;
                d += __shfl_xor(d, 1);
                d += __shfl_xor(d, 2);
                d += __shfl_xor(d, 4);
                d += __shfl_xor(d, 8);
                D[m][r] = D[m][r] * fD + d;
            }
        }
    }

    // ---- write per-block results ----
    float* dout = dts + (size_t)bid * HDIM;
    #pragma unroll
    for (int m = 0; m < 4; m++)
        #pragma unroll
        for (int r = 0; r < 4; r++)
            if (cl == 0) dout[wo + m * 16 + gr * 4 + r] = D[m][r];
    if (tid == 0) {
        stats[bid * 2]     = M_run;
        stats[bid * 2 + 1] = S_run;
    }
}

// ---- kernel 4: combine 4 block-quarters per batch ----
__global__ void k_comb(const float* __restrict__ stats, const float* __restrict__ dts,
                       const float* __restrict__ bref, float* __restrict__ out) {
    __shared__ float sm[NTB], sl[NTB];
    int b = blockIdx.x, tid = threadIdx.x;
    if (tid < NTB) {
        sm[tid] = stats[(b * NTB + tid) * 2];
        sl[tid] = stats[(b * NTB + tid) * 2 + 1];
    }
    __syncthreads();
    float m = -3.4e38f;
    #pragma unroll
    for (int j = 0; j < NTB; j++) m = fmaxf(m, sm[j]);
    float sc[NTB];
    float L = 0.f;
    #pragma unroll
    for (int j = 0; j < NTB; j++) { sc[j] = __expf(sm[j] - m); L += sc[j] * sl[j]; }
    float inv = 1.0f / L;
    float acc = 0.f;
    #pragma unroll
    for (int j = 0; j < NTB; j++)
        acc += sc[j] * dts[((size_t)b * NTB + j) * HDIM + tid];
    out[b * HDIM + tid] = acc * inv + bref[tid];
}

extern "C" void kernel_launch(void* const* d_in, const int* in_sizes, int n_in,
                              void* d_out, int out_size, void* d_ws, size_t ws_size,
                              hipStream_t stream) {
    const float* q    = (const float*)d_in[0];
    const float* ref  = (const float*)d_in[1];
    const int*   mask = (const int*)d_in[2];
    const float* v    = (const float*)d_in[3];
    const float* Wq   = (const float*)d_in[4];
    const float* bq   = (const float*)d_in[5];
    const float* Wref = (const float*)d_in[6];
    const float* bref = (const float*)d_in[7];
    float* out = (float*)d_out;

    char* ws = (char*)d_ws;
    unsigned short* wbf = (unsigned short*)ws;                 // 524288 B
    float* u1b   = (float*)(ws + 524288);                      // 262144 B
    float* stats = (float*)(ws + 524288 + 262144);             // 4096 B
    float* dts   = (float*)(ws + 524288 + 262144 + 4096);      // 1 MB

    k_cast_w<<<256, 256, 0, stream>>>(Wref, wbf);
    k_u1<<<BS, HDIM, 0, stream>>>(q, Wq, bq, bref, u1b);
    k_main<<<NBLK, NTHR, 0, stream>>>(ref, mask, v, wbf, u1b, stats, dts);
    k_comb<<<BS, HDIM, 0, stream>>>(stats, dts, bref, out);
}